// Round 5
// baseline (31983.514 us; speedup 1.0000x reference)
//
#include <hip/hip_runtime.h>
#include <math.h>

#define TT 2048
#define NB 64
#define EE 256
#define HH 256
#define PJ 16    // j-partitions recorded in part[] (unchanged layout)
#define XLD 288  // swizzled row: 256 + 4 pad per 32 floats
#define RS1 280  // red_s kc stride
#define RS2 72   // red_s batch stride

typedef float f32x4 __attribute__((ext_vector_type(4)));

__device__ __forceinline__ float sigf(float x) { return 1.f / (1.f + expf(-x)); }

// R10b: R9's 8-wave structure with the inter-WG exchange rebuilt.
//  - Publish: wave0 stores 64 plain 4B floats (coalesced) + ONE release
//    fence + ONE flag store per WG (was: 64 scattered 8B tagged atomics).
//  - Consume: waves 0-3 poll 16 flags in a single 64B line, one acquire
//    fence (L1 inv), then coalesced plain float4 loads of h from L2
//    (was: 1024 scattered 8B atomic polls that missed to HBM).
//  - emb loads are non-temporal so the 131MB emb stream stops evicting
//    hbuf from L2 (the cause of R9's +50MB HBM poll misses).
//  - emb prefetch issued at iteration start on waves 4-7 (non-polling, so
//    their in-flight loads are never drained by a poll's vmcnt wait);
//    tok_ns LDS removed (register token prefetch).
//  - 64KB dynamic LDS pad forces 1 WG/CU (kills the 2-WG-packing 36ms
//    outlier seen in R9).
// All per-value fp op orders identical to R9 (bitwise outputs, absmax 0).
__global__ __launch_bounds__(512, 2)
void lstm_kernel(const int* __restrict__ sent, const float* __restrict__ emb,
                 const float* __restrict__ W_ih, const float* __restrict__ W_hh,
                 const float* __restrict__ b_ih, const float* __restrict__ b_hh,
                 const float* __restrict__ W_z,
                 float* __restrict__ hbuf, unsigned* __restrict__ flags,
                 float* __restrict__ part)
{
    __shared__ float x_sw[4 * XLD];
    __shared__ float h_sw[4 * XLD];
    __shared__ float red_s[8 * RS1];
    __shared__ float p_s[64];

    const int tid  = threadIdx.x;
    // XCD-clustering swizzle (heuristic, as R6/R9)
    const int xcd  = blockIdx.x & 7;
    const int slot = blockIdx.x >> 3;       // 0..31
    const int grp  = xcd * 2 + (slot >> 4); // 0..15 batch group
    const int jgrp = slot & 15;             // 0..15 j-slice
    const int b0   = grp << 2;
    const int j0   = jgrp << 4;

    const int wv    = tid >> 6;             // 0..7
    const int lane  = tid & 63;
    const int bp    = wv & 1;               // batch pair (0: b0,b1  1: b2,b3)
    const int kc    = (wv >> 1) * 2 + (lane & 1);  // 0..7 k-chunk (32 floats)
    const int rg    = lane >> 1;            // 0..31 row-group (2 rows)
    const int kbase = kc << 5;

    // ---- W chunks -> VGPRs: 2 rows x 8 float4 per matrix = 128 VGPRs ----
    float4 wih_r[16], whh_r[16];
    #pragma unroll
    for (int i = 0; i < 2; ++i) {
        int lr = rg * 2 + i;                          // row 0..63
        long grow = (long)((lr >> 4) * HH + j0 + (lr & 15));
        const float4* wi = (const float4*)(W_ih + grow * EE + kbase);
        const float4* wh = (const float4*)(W_hh + grow * EE + kbase);
        #pragma unroll
        for (int mi = 0; mi < 8; ++mi) {
            wih_r[i * 8 + mi] = wi[mi];
            whh_r[i * 8 + mi] = wh[mi];
        }
    }

    // ---- wave0 epilogue state (one (b,jj) output per lane) ----
    const int eb  = lane >> 4;   // batch 0..3
    const int ejj = lane & 15;   // j within slice
    float bias_g[4]; float wz_r = 0.f; float c_reg = 0.f;
    if (wv == 0) {
        #pragma unroll
        for (int g = 0; g < 4; ++g)
            bias_g[g] = b_ih[g * HH + j0 + ejj] + b_hh[g * HH + j0 + ejj];
        wz_r = W_z[j0 + ejj];
    }

    // consumer fill mapping (waves 0-3 only): thread -> h[(b0+cb)][cj..cj+3]
    const int cb    = tid >> 6;              // 0..3 (valid for tid<256)
    const int cj    = (tid & 63) << 2;
    const int cphys = cj + ((cj >> 5) << 2);

    // staging role: waves 4-7 (never poll -> their prefetch stays in flight)
    const int st   = tid - 256;
    const int stb  = st >> 6;                // 0..3 (valid if st>=0)
    const int ste4 = st & 63;

    int tok_nxt = 0;
    if (st >= 0) {   // prologue: stage x(0), prefetch token for t=1
        int tk0 = sent[0 * NB + b0 + stb];
        f32x4 xv0 = __builtin_nontemporal_load(
            (const f32x4*)(emb + (long)tk0 * EE) + ste4);
        int phys = 4 * ste4 + ((ste4 >> 3) << 2);
        *(f32x4*)(&x_sw[stb * XLD + phys]) = xv0;
        tok_nxt = sent[1 * NB + b0 + stb];
    }
    __syncthreads();

    for (int t = 0; t < TT; ++t) {
        const bool pf = (t + 1 < TT);

        // ---- issue x(t+1) emb loads first (completes behind phase1+fill) --
        f32x4 xv;
        if (st >= 0 && pf) {
            xv = __builtin_nontemporal_load(
                (const f32x4*)(emb + (long)tok_nxt * EE) + ste4);
            if (t + 2 < TT) tok_nxt = sent[(t + 2) * NB + b0 + stb];
        }

        // ---- phase 1: x partials (x_sw staged previous iteration) ----
        float4 acc[2][2];   // [row i][batch jb]
        #pragma unroll
        for (int i = 0; i < 2; ++i)
            #pragma unroll
            for (int j = 0; j < 2; ++j)
                acc[i][j] = make_float4(0.f, 0.f, 0.f, 0.f);

        #pragma unroll
        for (int jb = 0; jb < 2; ++jb) {
            const float* xb = &x_sw[(2 * bp + jb) * XLD + kc * 36];
            #pragma unroll
            for (int mi = 0; mi < 8; ++mi) {
                float4 xv4 = *(const float4*)(xb + mi * 4);
                #pragma unroll
                for (int i = 0; i < 2; ++i) {
                    float4 w = wih_r[i * 8 + mi];
                    acc[i][jb].x += w.x * xv4.x; acc[i][jb].y += w.y * xv4.y;
                    acc[i][jb].z += w.z * xv4.z; acc[i][jb].w += w.w * xv4.w;
                }
            }
        }

        // ---- consume h_{t-1}: flag poll + acquire + coalesced loads ----
        if (t > 0 && tid < 256) {
            const unsigned want = (unsigned)t;   // h_{t-1} published with flag t
            unsigned f = want;
            if (lane < 16)
                f = __hip_atomic_load(&flags[grp * 16 + lane],
                                      __ATOMIC_RELAXED, __HIP_MEMORY_SCOPE_AGENT);
            while (!__all((int)(f - want) >= 0)) {
                if (lane < 16)
                    f = __hip_atomic_load(&flags[grp * 16 + lane],
                                          __ATOMIC_RELAXED, __HIP_MEMORY_SCOPE_AGENT);
            }
            __builtin_amdgcn_fence(__ATOMIC_ACQUIRE, "agent");
            float4 hv = *(const float4*)(
                hbuf + ((size_t)(((t - 1) & 1) * NB + b0 + cb)) * HH + cj);
            *(float4*)(&h_sw[cb * XLD + cphys]) = hv;
        }
        __syncthreads();   // B1: h_sw ready; x_sw(t) reads done

        // part-sum for step t-1: wave1 lanes 0..3, off the critical path
        if (t > 0 && wv == 1 && lane < 4) {
            float s = 0.f;
            #pragma unroll
            for (int jj = 0; jj < 16; ++jj) s += p_s[lane * 16 + jj];
            part[((size_t)(t - 1) * PJ + jgrp) * NB + b0 + lane] = s;
        }

        // ---- phase 2b: h partials into same accumulators ----
        if (t > 0) {
            #pragma unroll
            for (int jb = 0; jb < 2; ++jb) {
                const float* hb = &h_sw[(2 * bp + jb) * XLD + kc * 36];
                #pragma unroll
                for (int mi = 0; mi < 8; ++mi) {
                    float4 hv4 = *(const float4*)(hb + mi * 4);
                    #pragma unroll
                    for (int i = 0; i < 2; ++i) {
                        float4 w = whh_r[i * 8 + mi];
                        acc[i][jb].x += w.x * hv4.x; acc[i][jb].y += w.y * hv4.y;
                        acc[i][jb].z += w.z * hv4.z; acc[i][jb].w += w.w * hv4.w;
                    }
                }
            }
        }
        // horizontal-add partials, write to reduction scratch (float2 per b)
        #pragma unroll
        for (int jb = 0; jb < 2; ++jb) {
            int b = 2 * bp + jb;
            float2 v;
            v.x = (acc[0][jb].x + acc[0][jb].y) + (acc[0][jb].z + acc[0][jb].w);
            v.y = (acc[1][jb].x + acc[1][jb].y) + (acc[1][jb].z + acc[1][jb].w);
            *(float2*)(&red_s[kc * RS1 + b * RS2 + rg * 2]) = v;
        }
        if (st >= 0 && pf) {   // stage next x (x_sw readers finished pre-B1)
            int phys = 4 * ste4 + ((ste4 >> 3) << 2);
            *(f32x4*)(&x_sw[stb * XLD + phys]) = xv;
        }
        __syncthreads();   // B2: red_s ready; x_sw staged for t+1

        // ---- epilogue: wave0 (reduce + gates + publish + flag) ----
        // Waves 1-7 fall through to phase1(t+1); their red_s/x_sw writes for
        // t+1 happen after B1(t+1), which wave0 reaches only after its reads.
        if (wv == 0) {
            float sg[4];
            #pragma unroll
            for (int g = 0; g < 4; ++g) {
                float s = bias_g[g];
                #pragma unroll
                for (int k2 = 0; k2 < 8; ++k2)
                    s += red_s[k2 * RS1 + eb * RS2 + g * 16 + ejj];
                sg[g] = s;
            }
            float cn = sigf(sg[1]) * c_reg + sigf(sg[0]) * tanhf(sg[2]);
            float hn = sigf(sg[3]) * tanhf(cn);
            c_reg = cn;
            p_s[lane] = hn * wz_r;
            hbuf[((size_t)((t & 1) * NB + b0 + eb)) * HH + j0 + ejj] = hn;
            __builtin_amdgcn_fence(__ATOMIC_RELEASE, "agent");
            if (lane == 0)
                __hip_atomic_store(&flags[grp * 16 + jgrp], (unsigned)(t + 1),
                                   __ATOMIC_RELAXED, __HIP_MEMORY_SCOPE_AGENT);
        }
    }

    // final part-sum (t = TT-1)
    __syncthreads();
    if (wv == 1 && lane < 4) {
        float s = 0.f;
        #pragma unroll
        for (int jj = 0; jj < 16; ++jj) s += p_s[lane * 16 + jj];
        part[((size_t)(TT - 1) * PJ + jgrp) * NB + b0 + lane] = s;
    }
}

__global__ void pz_kernel(const float* __restrict__ part,
                          const float* __restrict__ noise,
                          const float* __restrict__ b_z,
                          float* __restrict__ out)
{
    int idx = blockIdx.x * blockDim.x + threadIdx.x;  // t*64 + b
    if (idx >= TT * NB) return;
    int t = idx >> 6, b = idx & 63;
    float s = b_z[0];
    #pragma unroll
    for (int jg = 0; jg < PJ; ++jg) s += part[(t * PJ + jg) * NB + b];
    float pz = 1.f / (1.f + expf(-s));
    out[idx] = pz;
    out[TT * NB + idx] = (noise[idx] < pz) ? 1.f : 0.f;
}

// One block per batch column: stable compaction of tokens where z==1.
__global__ void compact_kernel(const int* __restrict__ sent,
                               const float* __restrict__ zbuf,
                               float* __restrict__ rat,
                               float* __restrict__ zsz)
{
    __shared__ float rat_s[TT];
    __shared__ int scan_s[256];
    int b = blockIdx.x, tid = threadIdx.x;
    int zloc[8];
    int base = tid * 8;
    int c = 0;
    #pragma unroll
    for (int i = 0; i < 8; ++i) {
        zloc[i] = (zbuf[(base + i) * NB + b] != 0.f) ? 1 : 0;
        c += zloc[i];
    }
    scan_s[tid] = c;
    for (int i = tid; i < TT; i += 256) rat_s[i] = 0.f;
    __syncthreads();
    for (int off = 1; off < 256; off <<= 1) {
        int v = scan_s[tid];
        int add = (tid >= off) ? scan_s[tid - off] : 0;
        __syncthreads();
        scan_s[tid] = v + add;
        __syncthreads();
    }
    int total = scan_s[255];
    int pos = scan_s[tid] - c;  // exclusive prefix
    #pragma unroll
    for (int i = 0; i < 8; ++i) {
        if (zloc[i]) { rat_s[pos] = (float)sent[(base + i) * NB + b]; ++pos; }
    }
    __syncthreads();
    for (int i = tid; i < TT; i += 256) rat[i * NB + b] = rat_s[i];
    if (tid == 0) zsz[b] = (float)total;
}

extern "C" void kernel_launch(void* const* d_in, const int* in_sizes, int n_in,
                              void* d_out, int out_size, void* d_ws, size_t ws_size,
                              hipStream_t stream)
{
    const int*   sent  = (const int*)d_in[0];
    const float* noise = (const float*)d_in[1];
    const float* emb   = (const float*)d_in[2];
    const float* W_ih  = (const float*)d_in[3];
    const float* W_hh  = (const float*)d_in[4];
    const float* b_ih  = (const float*)d_in[5];
    const float* b_hh  = (const float*)d_in[6];
    const float* W_z   = (const float*)d_in[7];
    const float* b_z   = (const float*)d_in[8];
    float* out = (float*)d_out;

    char* ws = (char*)d_ws;
    float*    hbuf  = (float*)ws;                 // 2*64*256*4 = 128 KB
    unsigned* flags = (unsigned*)(ws + 131072);   // 16*16*4   = 1 KB
    float*    part  = (float*)(ws + 262144);      // 2048*16*64*4 = 8 MB

    // flags must start != any expected value (1..2048)
    (void)hipMemsetAsync(ws, 0, 132096, stream);

    // 64KB dynamic LDS on top of ~18.5KB static -> >80KB -> exactly 1 WG/CU
    lstm_kernel<<<256, 512, 65536, stream>>>(sent, emb, W_ih, W_hh, b_ih, b_hh,
                                             W_z, hbuf, flags, part);
    pz_kernel<<<(TT * NB) / 256, 256, 0, stream>>>(part, noise, b_z, out);
    compact_kernel<<<NB, 256, 0, stream>>>(sent, out + TT * NB,
                                           out + 2 * TT * NB, out + 3 * TT * NB);
}

// Round 6
// 7235.753 us; speedup vs baseline: 4.4202x; 4.4202x over previous
//
#include <hip/hip_runtime.h>
#include <math.h>

#define TT 2048
#define NB 64
#define EE 256
#define HH 256
#define PJ 16    // j-partitions recorded in part[] (unchanged layout)
#define XLD 288  // swizzled row: 256 + 4 pad per 32 floats
#define RS1 280  // red_s kc stride (mod 32 = 24)
#define RS2 72   // red_s batch stride (mod 32 = 8 -> epilogue reads conflict-free)

typedef float f32x4 __attribute__((ext_vector_type(4)));

__device__ __forceinline__ float sigf(float x) { return 1.f / (1.f + expf(-x)); }

__device__ __forceinline__ unsigned long long packh(unsigned tag, float v) {
    union { float f; unsigned u; } c; c.f = v;
    return ((unsigned long long)tag << 32) | (unsigned long long)c.u;
}

// R11: R6's LDS-optimal blocking (256 threads, 4 rows/thread, 128KB LDS
// volume/step -- half of R9's) combined with the lean 2-barrier schedule:
//  - wave0-fused register epilogue (reduce+gates+tagged publish), waves 1-3
//    run ahead into phase1(t+1)
//  - part-sum offloaded to wave1 at t+1 via p_s (no shfl chain -- R8's bug)
//  - red_s strides 280/72: epilogue reduce reads conflict-free (R8's bug)
//  - polls fresh after phase1, R6's exact tagged 8B agent-atomic protocol
//    (R10b's agent fences were catastrophic; no fences here)
//  - non-temporal emb loads (keep hbuf L2-resident; R9's polls missed to HBM)
//  - tok_ns LDS removed: wave-uniform scalar sent reads
//  - 64KB dynamic LDS (extern decl + opaque touch) forces 1 WG/CU exactly
// All per-value fp op orders identical to R6 (bitwise outputs, absmax 0).
__global__ __launch_bounds__(256, 1)
void lstm_kernel(const int* __restrict__ sent, const float* __restrict__ emb,
                 const float* __restrict__ W_ih, const float* __restrict__ W_hh,
                 const float* __restrict__ b_ih, const float* __restrict__ b_hh,
                 const float* __restrict__ W_z,
                 unsigned long long* __restrict__ hbuf,
                 float* __restrict__ part)
{
    __shared__ float x_sw[4 * XLD];
    __shared__ float h_sw[4 * XLD];
    __shared__ float red_s[8 * RS1];
    __shared__ float p_s[64];
    extern __shared__ float dyn_pad[];   // 64KB occupancy pad (launch config)

    const int tid  = threadIdx.x;
    // opaque touch so the dynamic LDS allocation is never elided
    if (tid == 0 && sent[0] < 0) ((volatile float*)dyn_pad)[0] = 0.f;

    // XCD-clustering swizzle (heuristic, as R6/R9)
    const int xcd  = blockIdx.x & 7;
    const int slot = blockIdx.x >> 3;       // 0..31
    const int grp  = xcd * 2 + (slot >> 4); // 0..15 batch group
    const int jgrp = slot & 15;             // 0..15 j-slice
    const int b0   = grp << 2;
    const int j0   = jgrp << 4;

    const int wv    = tid >> 6;             // 0..3
    const int lane  = tid & 63;
    const int rg    = lane >> 2;            // 0..15 row-group (4 rows)
    const int klow  = lane & 3;
    const int kc    = (wv >> 1) * 4 + klow; // 0..7  k-chunk (32 floats)
    const int bp    = wv & 1;               // batch pair
    const int kbase = kc << 5;

    // ---- W chunks -> VGPRs (R6 blocking: 4 rows x 8 float4 x 2 mats) ----
    float4 wih_r[32], whh_r[32];
    #pragma unroll
    for (int i = 0; i < 4; ++i) {
        int lr_i = rg * 4 + i;
        long grow = (long)((lr_i >> 4) * HH + j0 + (lr_i & 15));
        const float4* wi = (const float4*)(W_ih + grow * EE + kbase);
        const float4* wh = (const float4*)(W_hh + grow * EE + kbase);
        #pragma unroll
        for (int mi = 0; mi < 8; ++mi) {
            wih_r[i * 8 + mi] = wi[mi];
            whh_r[i * 8 + mi] = wh[mi];
        }
    }

    // ---- wave0 epilogue state (one (b,jj) output per lane) ----
    const int eb  = lane >> 4;   // batch 0..3
    const int ejj = lane & 15;   // j within slice
    float bias_g[4]; float wz_r = 0.f; float c_reg = 0.f;
    if (wv == 0) {
        #pragma unroll
        for (int g = 0; g < 4; ++g)
            bias_g[g] = b_ih[g * HH + j0 + ejj] + b_hh[g * HH + j0 + ejj];
        wz_r = W_z[j0 + ejj];
    }

    // consumer fill mapping: this thread loads h[(b0+cb)][cj..cj+3]
    const int cb    = tid >> 6;
    const int cj    = (tid & 63) << 2;
    const int cphys = cj + ((cj >> 5) << 2);

    // staging mapping (all threads): x[(b0+sb)][se4*4 ..]
    const int sb  = tid >> 6;
    const int se4 = tid & 63;

    {   // prologue: stage x for t=0 (swizzled, nt load, uniform token read)
        int tk0 = sent[0 * NB + b0 + sb];
        f32x4 xv0 = __builtin_nontemporal_load(
            (const f32x4*)(emb + (long)tk0 * EE) + se4);
        int phys = 4 * se4 + ((se4 >> 3) << 2);
        *(f32x4*)(&x_sw[sb * XLD + phys]) = xv0;
    }
    __syncthreads();

    for (int t = 0; t < TT; ++t) {
        const bool pf = (t + 1 < TT);

        // ---- phase 1: x partials (x_sw staged previous iteration) ----
        float4 acc4[4][2];
        #pragma unroll
        for (int i = 0; i < 4; ++i)
            #pragma unroll
            for (int j = 0; j < 2; ++j)
                acc4[i][j] = make_float4(0.f, 0.f, 0.f, 0.f);

        #pragma unroll
        for (int j = 0; j < 2; ++j) {
            const float* xb = &x_sw[(2 * bp + j) * XLD + kc * 36];
            #pragma unroll
            for (int mi = 0; mi < 8; ++mi) {
                float4 xv4 = *(const float4*)(xb + mi * 4);
                #pragma unroll
                for (int i = 0; i < 4; ++i) {
                    float4 w = wih_r[i * 8 + mi];
                    acc4[i][j].x += w.x * xv4.x; acc4[i][j].y += w.y * xv4.y;
                    acc4[i][j].z += w.z * xv4.z; acc4[i][j].w += w.w * xv4.w;
                }
            }
        }

        // ---- spin-consume h_{t-1} (R6's exact tagged protocol, fresh) ----
        if (t > 0) {
            const unsigned want = (unsigned)t;   // h_{t-1} carries tag t
            unsigned long long* hp =
                hbuf + ((size_t)(((t - 1) & 1) * NB + b0 + cb)) * HH + cj;
            unsigned long long v0, v1, v2, v3;
            v0 = __hip_atomic_load(hp + 0, __ATOMIC_RELAXED, __HIP_MEMORY_SCOPE_AGENT);
            v1 = __hip_atomic_load(hp + 1, __ATOMIC_RELAXED, __HIP_MEMORY_SCOPE_AGENT);
            v2 = __hip_atomic_load(hp + 2, __ATOMIC_RELAXED, __HIP_MEMORY_SCOPE_AGENT);
            v3 = __hip_atomic_load(hp + 3, __ATOMIC_RELAXED, __HIP_MEMORY_SCOPE_AGENT);
            while ((unsigned)(v0 >> 32) != want)
                v0 = __hip_atomic_load(hp + 0, __ATOMIC_RELAXED, __HIP_MEMORY_SCOPE_AGENT);
            while ((unsigned)(v1 >> 32) != want)
                v1 = __hip_atomic_load(hp + 1, __ATOMIC_RELAXED, __HIP_MEMORY_SCOPE_AGENT);
            while ((unsigned)(v2 >> 32) != want)
                v2 = __hip_atomic_load(hp + 2, __ATOMIC_RELAXED, __HIP_MEMORY_SCOPE_AGENT);
            while ((unsigned)(v3 >> 32) != want)
                v3 = __hip_atomic_load(hp + 3, __ATOMIC_RELAXED, __HIP_MEMORY_SCOPE_AGENT);
            union { unsigned u; float f; } c0, c1, c2, c3;
            c0.u = (unsigned)v0; c1.u = (unsigned)v1;
            c2.u = (unsigned)v2; c3.u = (unsigned)v3;
            *(float4*)(&h_sw[cb * XLD + cphys]) =
                make_float4(c0.f, c1.f, c2.f, c3.f);
        }
        __syncthreads();   // B1: h_sw ready; x_sw(t) reads done

        // part-sum for step t-1: wave1 lanes 0..3, off the critical path
        // (p_s written by wave0 post-B2(t-1); next write post-B2(t))
        if (t > 0 && wv == 1 && lane < 4) {
            float s = 0.f;
            #pragma unroll
            for (int jj = 0; jj < 16; ++jj) s += p_s[lane * 16 + jj];
            part[((size_t)(t - 1) * PJ + jgrp) * NB + b0 + lane] = s;
        }

        f32x4 xv;          // emb prefetch (nt; completes behind h-FMAs)
        if (pf) {
            int tkn = sent[(t + 1) * NB + b0 + sb];   // wave-uniform scalar
            xv = __builtin_nontemporal_load(
                (const f32x4*)(emb + (long)tkn * EE) + se4);
        }

        // ---- phase 2b: h partials into same accumulators ----
        if (t > 0) {
            #pragma unroll
            for (int j = 0; j < 2; ++j) {
                const float* hb = &h_sw[(2 * bp + j) * XLD + kc * 36];
                #pragma unroll
                for (int mi = 0; mi < 8; ++mi) {
                    float4 hv4 = *(const float4*)(hb + mi * 4);
                    #pragma unroll
                    for (int i = 0; i < 4; ++i) {
                        float4 w = whh_r[i * 8 + mi];
                        acc4[i][j].x += w.x * hv4.x; acc4[i][j].y += w.y * hv4.y;
                        acc4[i][j].z += w.z * hv4.z; acc4[i][j].w += w.w * hv4.w;
                    }
                }
            }
        }
        // horizontal-add partials, write to reduction scratch
        #pragma unroll
        for (int j = 0; j < 2; ++j) {
            int b = 2 * bp + j;
            float4 v;
            v.x = (acc4[0][j].x + acc4[0][j].y) + (acc4[0][j].z + acc4[0][j].w);
            v.y = (acc4[1][j].x + acc4[1][j].y) + (acc4[1][j].z + acc4[1][j].w);
            v.z = (acc4[2][j].x + acc4[2][j].y) + (acc4[2][j].z + acc4[2][j].w);
            v.w = (acc4[3][j].x + acc4[3][j].y) + (acc4[3][j].z + acc4[3][j].w);
            *(float4*)(&red_s[kc * RS1 + b * RS2 + rg * 4]) = v;
        }
        if (pf) {          // stage next x (x_sw readers finished pre-B1)
            int phys = 4 * se4 + ((se4 >> 3) << 2);
            *(f32x4*)(&x_sw[sb * XLD + phys]) = xv;
        }
        __syncthreads();   // B2: red_s ready; x_sw staged for t+1

        // ---- epilogue: wave0 only (reduce + gates + tagged publish + p_s)
        // Waves 1-3 fall through to phase1(t+1); their red_s/x_sw writes for
        // t+1 happen after B1(t+1), which wave0 reaches only after its reads.
        if (wv == 0) {
            float sg[4];
            #pragma unroll
            for (int g = 0; g < 4; ++g) {
                float s = bias_g[g];
                #pragma unroll
                for (int k2 = 0; k2 < 8; ++k2)
                    s += red_s[k2 * RS1 + eb * RS2 + g * 16 + ejj];
                sg[g] = s;
            }
            float cn = sigf(sg[1]) * c_reg + sigf(sg[0]) * tanhf(sg[2]);
            float hn = sigf(sg[3]) * tanhf(cn);
            c_reg = cn;
            p_s[lane] = hn * wz_r;
            __hip_atomic_store(
                hbuf + ((size_t)((t & 1) * NB + b0 + eb)) * HH + j0 + ejj,
                packh((unsigned)(t + 1), hn),
                __ATOMIC_RELAXED, __HIP_MEMORY_SCOPE_AGENT);
        }
    }

    // final part-sum (t = TT-1)
    __syncthreads();
    if (wv == 1 && lane < 4) {
        float s = 0.f;
        #pragma unroll
        for (int jj = 0; jj < 16; ++jj) s += p_s[lane * 16 + jj];
        part[((size_t)(TT - 1) * PJ + jgrp) * NB + b0 + lane] = s;
    }
}

__global__ void pz_kernel(const float* __restrict__ part,
                          const float* __restrict__ noise,
                          const float* __restrict__ b_z,
                          float* __restrict__ out)
{
    int idx = blockIdx.x * blockDim.x + threadIdx.x;  // t*64 + b
    if (idx >= TT * NB) return;
    int t = idx >> 6, b = idx & 63;
    float s = b_z[0];
    #pragma unroll
    for (int jg = 0; jg < PJ; ++jg) s += part[(t * PJ + jg) * NB + b];
    float pz = 1.f / (1.f + expf(-s));
    out[idx] = pz;
    out[TT * NB + idx] = (noise[idx] < pz) ? 1.f : 0.f;
}

// One block per batch column: stable compaction of tokens where z==1.
__global__ void compact_kernel(const int* __restrict__ sent,
                               const float* __restrict__ zbuf,
                               float* __restrict__ rat,
                               float* __restrict__ zsz)
{
    __shared__ float rat_s[TT];
    __shared__ int scan_s[256];
    int b = blockIdx.x, tid = threadIdx.x;
    int zloc[8];
    int base = tid * 8;
    int c = 0;
    #pragma unroll
    for (int i = 0; i < 8; ++i) {
        zloc[i] = (zbuf[(base + i) * NB + b] != 0.f) ? 1 : 0;
        c += zloc[i];
    }
    scan_s[tid] = c;
    for (int i = tid; i < TT; i += 256) rat_s[i] = 0.f;
    __syncthreads();
    for (int off = 1; off < 256; off <<= 1) {
        int v = scan_s[tid];
        int add = (tid >= off) ? scan_s[tid - off] : 0;
        __syncthreads();
        scan_s[tid] = v + add;
        __syncthreads();
    }
    int total = scan_s[255];
    int pos = scan_s[tid] - c;  // exclusive prefix
    #pragma unroll
    for (int i = 0; i < 8; ++i) {
        if (zloc[i]) { rat_s[pos] = (float)sent[(base + i) * NB + b]; ++pos; }
    }
    __syncthreads();
    for (int i = tid; i < TT; i += 256) rat[i * NB + b] = rat_s[i];
    if (tid == 0) zsz[b] = (float)total;
}

extern "C" void kernel_launch(void* const* d_in, const int* in_sizes, int n_in,
                              void* d_out, int out_size, void* d_ws, size_t ws_size,
                              hipStream_t stream)
{
    const int*   sent  = (const int*)d_in[0];
    const float* noise = (const float*)d_in[1];
    const float* emb   = (const float*)d_in[2];
    const float* W_ih  = (const float*)d_in[3];
    const float* W_hh  = (const float*)d_in[4];
    const float* b_ih  = (const float*)d_in[5];
    const float* b_hh  = (const float*)d_in[6];
    const float* W_z   = (const float*)d_in[7];
    const float* b_z   = (const float*)d_in[8];
    float* out = (float*)d_out;

    char* ws = (char*)d_ws;
    unsigned long long* hbuf = (unsigned long long*)ws;     // 2*64*256*8 = 256 KB
    float* part = (float*)(ws + 262144);                    // 2048*16*64*4 = 8 MB

    // tags must start != any expected tag (1..2048)
    (void)hipMemsetAsync(hbuf, 0, 2 * NB * HH * sizeof(unsigned long long), stream);

    // 64KB dynamic LDS on top of ~18.5KB static -> ~83KB -> exactly 1 WG/CU
    lstm_kernel<<<256, 256, 65536, stream>>>(sent, emb, W_ih, W_hh, b_ih, b_hh,
                                             W_z, hbuf, part);
    pz_kernel<<<(TT * NB) / 256, 256, 0, stream>>>(part, noise, b_z, out);
    compact_kernel<<<NB, 256, 0, stream>>>(sent, out + TT * NB,
                                           out + 2 * TT * NB, out + 3 * TT * NB);
}